// Round 5
// baseline (466.102 us; speedup 1.0000x reference)
//
#include <hip/hip_runtime.h>
#include <hip/hip_bf16.h>

// EncoderAttention4 v6: chunked load batching for memory-level parallelism.
// B=65536, NEGO=48, NADO=24, NADOAG=5, E=256, H=4, AD=64. Out: (B,112) fp32.
//
// v5 post-mortem: kernel fits in 64 VGPRs and the scheduler issues B-fragment
// L2 loads (~112/wave/block, 200-400cy each) one kb at a time -> ~1-2
// outstanding -> exposed-latency dominates (MfmaUtil 13%, VALU 18%, L2 24%,
// HBM 1.5%: everything idle). v6: every GEMM loads B and A fragments for a
// chunk of C kb-steps into register arrays BEFORE the chunk's MFMAs,
// forcing 4-16 outstanding loads per wave. C per phase sized to the 128-reg
// budget of __launch_bounds__(512,4).

typedef __bf16 bf16x8 __attribute__((ext_vector_type(8)));
typedef __bf16 bf16x4 __attribute__((ext_vector_type(4)));
typedef float  f32x4  __attribute__((ext_vector_type(4)));

// Workspace layout (bf16 elements), unchanged.
#define OFF_EGO0 0        // [256][64]  (K=48 padded to 64)
#define OFF_EGO1 16384    // [256][256]
#define OFF_ADO0 81920    // [256][32]  (K=25 padded to 32)
#define OFF_ADO1 90112    // [256][256]
#define OFF_SEL  155648   // [256][256] col c -> head c>>6, d c&63
#define OFF_KEY  221184
#define OFF_LAT  286720
#define OFF_PROJ 352256   // [64][256]
#define WS_ELEMS 368640

__global__ __launch_bounds__(256) void prep_weights(
    const float* __restrict__ ew0, const float* __restrict__ ew1,
    const float* __restrict__ aw0, const float* __restrict__ aw1,
    const float* __restrict__ keyw, const float* __restrict__ selw,
    const float* __restrict__ latw, const float* __restrict__ projw,
    __bf16* __restrict__ ws)
{
  int i = blockIdx.x * 256 + threadIdx.x;
  if (i >= WS_ELEMS) return;
  float v;
  if (i < OFF_EGO1)      { int j=i;          int c=j>>6, k=j&63;  v = (k<48) ? ew0[k*256+c] : 0.f; }
  else if (i < OFF_ADO0) { int j=i-OFF_EGO1; int c=j>>8, k=j&255; v = ew1[k*256+c]; }
  else if (i < OFF_ADO1) { int j=i-OFF_ADO0; int c=j>>5, k=j&31;  v = (k<25) ? aw0[k*256+c] : 0.f; }
  else if (i < OFF_SEL)  { int j=i-OFF_ADO1; int c=j>>8, k=j&255; v = aw1[k*256+c]; }
  else if (i < OFF_KEY)  { int j=i-OFF_SEL;  int c=j>>8, k=j&255; v = selw[(c>>6)*16384 + k*64 + (c&63)]; }
  else if (i < OFF_LAT)  { int j=i-OFF_KEY;  int c=j>>8, k=j&255; v = keyw[(c>>6)*16384 + k*64 + (c&63)]; }
  else if (i < OFF_PROJ) { int j=i-OFF_LAT;  int c=j>>8, k=j&255; v = latw[(c>>6)*16384 + k*64 + (c&63)]; }
  else                   { int j=i-OFF_PROJ; int c=j>>8, k=j&255; v = projw[k*64+c]; }
  ws[i] = (__bf16)v;
}

// XOR-swizzled LDS accessors. byte ^= (row&7)<<4.
__device__ __forceinline__ bf16x8 lds_loadA(const __bf16* base, int row, int kByte, int rowBytes) {
  int off = (row * rowBytes + kByte) ^ ((row & 7) << 4);
  return *reinterpret_cast<const bf16x8*>(reinterpret_cast<const char*>(base) + off);
}
__device__ __forceinline__ void lds_store_bf16(__bf16* base, int row, int col, __bf16 v) {
  int off = (row * 512 + col * 2) ^ ((row & 7) << 4);  // 256-col tiles only
  *reinterpret_cast<__bf16*>(reinterpret_cast<char*>(base) + off) = v;
}

// LDS pool (bytes). Aliased regions with phase-disjoint lifetimes (as v5).
#define P_ADO2   0
#define P_EGOIN  0
#define P_EGOH1  2048
#define P_ADOIN  24576
#define P_EGOH2  40960
#define P_PROJIN 40960
#define P_H1     49152
#define P_OBSRAW 49152
#define P_OUT    73728
#define POOL_BYTES 77824   // 76KB -> 2 blocks/CU (152KB of 160KB)

// C(out 16R rows x 32 cols/wave) = act(A @ WT^T + bias). Column-split:
// wave w owns cols w*32 + c2*16 + lr. B loaded once per block.
// CHUNKED: loads for C kb-steps are issued as a batch (register arrays)
// before the chunk's MFMAs -> 2*C outstanding vmem loads per wave.
template<int KP, int R, int C, bool ACT>
__device__ __forceinline__ void gemm_block(const __bf16* __restrict__ sA, int aRow0,
                                           __bf16* __restrict__ sC, int cRow0,
                                           const __bf16* __restrict__ WT,
                                           const float* __restrict__ bias,
                                           int w, int lr, int lg)
{
  constexpr int NKB = KP / 32;
  static_assert(NKB % C == 0, "chunk must divide NKB");
  f32x4 acc[R][2];
  #pragma unroll
  for (int t = 0; t < R; ++t) {
    acc[t][0] = f32x4{0.f,0.f,0.f,0.f};
    acc[t][1] = f32x4{0.f,0.f,0.f,0.f};
  }
  const int col0 = w*32 + lr;
  #pragma unroll
  for (int kc = 0; kc < NKB; kc += C) {
    // batch: issue all B loads first (longest latency), then A ds_reads
    bf16x8 bfr[C][2];
    #pragma unroll
    for (int j = 0; j < C; ++j)
      #pragma unroll
      for (int c2 = 0; c2 < 2; ++c2)
        bfr[j][c2] = *reinterpret_cast<const bf16x8*>(
            WT + (col0 + c2*16)*KP + (kc+j)*32 + lg*8);
    bf16x8 af[C][R];
    #pragma unroll
    for (int j = 0; j < C; ++j)
      #pragma unroll
      for (int t = 0; t < R; ++t)
        af[j][t] = lds_loadA(sA, aRow0 + t*16 + lr, (kc+j)*64 + lg*16, KP*2);
    #pragma unroll
    for (int j = 0; j < C; ++j)
      #pragma unroll
      for (int c2 = 0; c2 < 2; ++c2)
        #pragma unroll
        for (int t = 0; t < R; ++t)
          acc[t][c2] = __builtin_amdgcn_mfma_f32_16x16x32_bf16(af[j][t], bfr[j][c2], acc[t][c2], 0, 0, 0);
  }
  #pragma unroll
  for (int c2 = 0; c2 < 2; ++c2) {
    const int col = col0 + c2*16;
    const float bv = bias[col];
    #pragma unroll
    for (int t = 0; t < R; ++t) {
      #pragma unroll
      for (int e = 0; e < 4; ++e) {
        float x = acc[t][c2][e] + bv;
        if (ACT) x = x > 0.f ? x : 0.01f * x;
        lds_store_bf16(sC, cRow0 + t*16 + lg*4 + e, col, (__bf16)x);
      }
    }
  }
}

__global__ __launch_bounds__(512, 4) void fused_kernel(
    const float* __restrict__ obs,
    const float* __restrict__ eb0, const float* __restrict__ eb1,
    const float* __restrict__ ab0, const float* __restrict__ ab1,
    const float* __restrict__ latb, const float* __restrict__ projb,
    const __bf16* __restrict__ ws,
    float* __restrict__ out)
{
  const int tid = threadIdx.x;
  const int w  = tid >> 6;   // 8 waves
  const int l  = tid & 63;
  const int lr = l & 15;
  const int lg = l >> 4;
  const int b0 = blockIdx.x * 16;

  __shared__ __align__(16) char pool[POOL_BYTES];
  __bf16* sEgoIn = reinterpret_cast<__bf16*>(pool + P_EGOIN);
  __bf16* sEgoH1 = reinterpret_cast<__bf16*>(pool + P_EGOH1);
  __bf16* sAdoIn = reinterpret_cast<__bf16*>(pool + P_ADOIN);
  __bf16* sEgoH2 = reinterpret_cast<__bf16*>(pool + P_EGOH2);
  __bf16* sProj  = reinterpret_cast<__bf16*>(pool + P_PROJIN);
  __bf16* sAdo2  = reinterpret_cast<__bf16*>(pool + P_ADO2);
  __bf16* sH1    = reinterpret_cast<__bf16*>(pool + P_H1);
  float*  sObsF  = reinterpret_cast<float*>(pool + P_OBSRAW);
  float*  sLogF  = reinterpret_cast<float*>(pool + P_OUT);
  float*  sOutF  = reinterpret_cast<float*>(pool + P_OUT);

  // ---- phase 1a: coalesced obs -> LDS (fp32) + NT fp32 passthrough out[:, :48]
  {
    const f32x4* o4 = reinterpret_cast<const f32x4*>(obs);
    #pragma unroll
    for (int idx = tid; idx < 672; idx += 512) {   // 16 rows x 42 f32x4
      int row = idx / 42, c4 = idx % 42;
      f32x4 v = o4[(size_t)(b0+row)*42 + c4];
      *reinterpret_cast<f32x4*>(sObsF + row*168 + c4*4) = v;
      if (c4 < 12)
        __builtin_nontemporal_store(v,
            reinterpret_cast<f32x4*>(out + (size_t)(b0+row)*112 + c4*4));
    }
  }
  __syncthreads();

  // ---- phase 1b: build bf16 inputs from LDS fp32
  {
    if (tid < 192) {            // ego: 16 rows x 12 f32x4
      int row = tid / 12, c4 = tid % 12;
      f32x4 v = *reinterpret_cast<const f32x4*>(sObsF + row*168 + c4*4);
      bf16x4 bv = { (__bf16)v[0], (__bf16)v[1], (__bf16)v[2], (__bf16)v[3] };
      int off = (row*128 + c4*8) ^ ((row&7)<<4);
      *reinterpret_cast<bf16x4*>(reinterpret_cast<char*>(sEgoIn) + off) = bv;
    } else if (tid < 256) {     // ego zero pad cols 48..63
      int t = tid - 192;
      int row = t >> 2, ch = t & 3;
      bf16x4 z = {};
      int off = (row*128 + 96 + ch*8) ^ ((row&7)<<4);
      *reinterpret_cast<bf16x4*>(reinterpret_cast<char*>(sEgoIn) + off) = z;
    }
    if (tid >= 256 && tid < 496) {  // ado gather: 80 lds rows x 3 chunks of 8
      int t = tid - 256;
      int ldsrow = t / 3, p = t % 3;
      int n = ldsrow >> 4, r = ldsrow & 15;
      const float* orow = sObsF + r*168 + 48;
      bf16x8 v;
      #pragma unroll
      for (int j = 0; j < 8; ++j) v[j] = (__bf16)orow[(p*8+j)*5 + n];
      int off = (ldsrow*64 + p*16) ^ ((ldsrow&7)<<4);
      *reinterpret_cast<bf16x8*>(reinterpret_cast<char*>(sAdoIn) + off) = v;
    }
    if (tid >= 432) {               // cols 24..31: teamid + zero pad
      int t = tid - 432;            // 0..79
      int n = t >> 4;
      bf16x8 v = {};
      v[0] = (__bf16)((n >= 2) ? 1.0f : 0.0f);   // team_ids[1:6] = 0,0,1,1,1
      int off = (t*64 + 48) ^ ((t&7)<<4);
      *reinterpret_cast<bf16x8*>(reinterpret_cast<char*>(sAdoIn) + off) = v;
    }
  }
  __syncthreads();

  // ---- phase 2: ego0 + ado0 (agents 0..2 -> sH1 rows 0..47)
  gemm_block<64, 1, 2, true>(sEgoIn, 0, sEgoH1, 0, ws + OFF_EGO0, eb0, w, lr, lg);
  gemm_block<32, 3, 1, true>(sAdoIn, 0, sH1,    0, ws + OFF_ADO0, ab0, w, lr, lg);
  __syncthreads();

  // ---- phase 3: ego1 (C=8: all 16 B loads in flight)
  gemm_block<256, 1, 8, true>(sEgoH1, 0, sEgoH2, 0, ws + OFF_EGO1, eb1, w, lr, lg);
  __syncthreads();

  // ---- phase 4: sel (regs, 1/8 folded, C=4 batching) + ado1 agents 0..2
  f32x4 slct[2];
  {
    const __bf16* WT = ws + OFF_SEL;
    slct[0] = f32x4{0.f,0.f,0.f,0.f};
    slct[1] = f32x4{0.f,0.f,0.f,0.f};
    #pragma unroll
    for (int kc = 0; kc < 8; kc += 4) {
      bf16x8 bfr[4][2];
      #pragma unroll
      for (int j = 0; j < 4; ++j)
        #pragma unroll
        for (int c2 = 0; c2 < 2; ++c2)
          bfr[j][c2] = *reinterpret_cast<const bf16x8*>(
              WT + (w*32 + c2*16 + lr)*256 + (kc+j)*32 + lg*8);
      bf16x8 af[4];
      #pragma unroll
      for (int j = 0; j < 4; ++j)
        af[j] = lds_loadA(sEgoH2, lr, (kc+j)*64 + lg*16, 512);
      #pragma unroll
      for (int j = 0; j < 4; ++j)
        #pragma unroll
        for (int c2 = 0; c2 < 2; ++c2)
          slct[c2] = __builtin_amdgcn_mfma_f32_16x16x32_bf16(af[j], bfr[j][c2], slct[c2], 0, 0, 0);
    }
    slct[0] *= 0.125f;   // fold 1/sqrt(AD) into slct
    slct[1] *= 0.125f;
  }
  gemm_block<256, 3, 4, true>(sH1, 0, sAdo2, 0, ws + OFF_ADO1, ab1, w, lr, lg);
  __syncthreads();

  // ---- phase 5: ado0 agents 3..4 -> sH1 rows 0..31
  gemm_block<32, 2, 1, true>(sAdoIn, 48, sH1, 0, ws + OFF_ADO0, ab0, w, lr, lg);
  __syncthreads();

  // ---- phase 6: ado1 agents 3..4 -> sAdo2 rows 48..79
  gemm_block<256, 2, 4, true>(sH1, 0, sAdo2, 48, ws + OFF_ADO1, ab1, w, lr, lg);
  __syncthreads();

  // ---- phase 7a: key pass, chunked C=2 (kacc 40 + af 40 + bk 16 regs)
  f32x4 part[5];
  {
    const __bf16* WK = ws + OFF_KEY;
    f32x4 kacc[5][2];
    #pragma unroll
    for (int n = 0; n < 5; ++n) {
      kacc[n][0] = f32x4{0.f,0.f,0.f,0.f};
      kacc[n][1] = f32x4{0.f,0.f,0.f,0.f};
    }
    #pragma unroll
    for (int kc = 0; kc < 8; kc += 2) {
      bf16x8 bk[2][2];
      #pragma unroll
      for (int j = 0; j < 2; ++j)
        #pragma unroll
        for (int c2 = 0; c2 < 2; ++c2)
          bk[j][c2] = *reinterpret_cast<const bf16x8*>(
              WK + (w*32 + c2*16 + lr)*256 + (kc+j)*32 + lg*8);
      bf16x8 af[2][5];
      #pragma unroll
      for (int j = 0; j < 2; ++j)
        #pragma unroll
        for (int n = 0; n < 5; ++n)
          af[j][n] = lds_loadA(sAdo2, n*16 + lr, (kc+j)*64 + lg*16, 512);
      #pragma unroll
      for (int j = 0; j < 2; ++j)
        #pragma unroll
        for (int c2 = 0; c2 < 2; ++c2)
          #pragma unroll
          for (int n = 0; n < 5; ++n)
            kacc[n][c2] = __builtin_amdgcn_mfma_f32_16x16x32_bf16(af[j][n], bk[j][c2], kacc[n][c2], 0, 0, 0);
    }
    #pragma unroll
    for (int n = 0; n < 5; ++n)
      part[n] = kacc[n][0]*slct[0] + kacc[n][1]*slct[1];
  }
  // reduce over lr lanes (sum over this wave's 32 d-dims)
  #pragma unroll
  for (int n = 0; n < 5; ++n) {
    #pragma unroll
    for (int m = 1; m < 16; m <<= 1) {
      part[n][0] += __shfl_xor(part[n][0], m);
      part[n][1] += __shfl_xor(part[n][1], m);
      part[n][2] += __shfl_xor(part[n][2], m);
      part[n][3] += __shfl_xor(part[n][3], m);
    }
  }
  // publish wave partials: sLogF[w][n][row] (f32x4 per (w,n,lg))
  #pragma unroll
  for (int n = 0; n < 5; ++n)
    if (lr == n)
      *reinterpret_cast<f32x4*>(sLogF + (w*5 + n)*16 + lg*4) = part[n];
  __syncthreads();
  // full logits = this wave's partial + partner wave's partial; exact softmax
  f32x4 p[5];
  {
    f32x4 lt[5];
    #pragma unroll
    for (int n = 0; n < 5; ++n)
      lt[n] = *reinterpret_cast<const f32x4*>(sLogF + (w*5 + n)*16 + lg*4)
            + *reinterpret_cast<const f32x4*>(sLogF + ((w^1)*5 + n)*16 + lg*4);
    f32x4 mx = lt[0];
    #pragma unroll
    for (int n = 1; n < 5; ++n)
      #pragma unroll
      for (int e = 0; e < 4; ++e) mx[e] = fmaxf(mx[e], lt[n][e]);
    f32x4 s = f32x4{0.f,0.f,0.f,0.f};
    #pragma unroll
    for (int n = 0; n < 5; ++n) {
      #pragma unroll
      for (int e = 0; e < 4; ++e) p[n][e] = __expf(lt[n][e] - mx[e]);
      s += p[n];
    }
    f32x4 inv;
    #pragma unroll
    for (int e = 0; e < 4; ++e) inv[e] = 1.0f / s[e];
    #pragma unroll
    for (int n = 0; n < 5; ++n) p[n] *= inv;
  }

  // ---- phase 7b: lat pass, same chunked shape; agg in regs
  f32x4 agg[2];
  agg[0] = f32x4{0.f,0.f,0.f,0.f};
  agg[1] = f32x4{0.f,0.f,0.f,0.f};
  {
    const __bf16* WL = ws + OFF_LAT;
    f32x4 lacc[5][2];
    #pragma unroll
    for (int n = 0; n < 5; ++n) {
      lacc[n][0] = f32x4{0.f,0.f,0.f,0.f};
      lacc[n][1] = f32x4{0.f,0.f,0.f,0.f};
    }
    #pragma unroll
    for (int kc = 0; kc < 8; kc += 2) {
      bf16x8 bl[2][2];
      #pragma unroll
      for (int j = 0; j < 2; ++j)
        #pragma unroll
        for (int c2 = 0; c2 < 2; ++c2)
          bl[j][c2] = *reinterpret_cast<const bf16x8*>(
              WL + (w*32 + c2*16 + lr)*256 + (kc+j)*32 + lg*8);
      bf16x8 af[2][5];
      #pragma unroll
      for (int j = 0; j < 2; ++j)
        #pragma unroll
        for (int n = 0; n < 5; ++n)
          af[j][n] = lds_loadA(sAdo2, n*16 + lr, (kc+j)*64 + lg*16, 512);
      #pragma unroll
      for (int j = 0; j < 2; ++j)
        #pragma unroll
        for (int c2 = 0; c2 < 2; ++c2)
          #pragma unroll
          for (int n = 0; n < 5; ++n)
            lacc[n][c2] = __builtin_amdgcn_mfma_f32_16x16x32_bf16(af[j][n], bl[j][c2], lacc[n][c2], 0, 0, 0);
    }
    #pragma unroll
    for (int c2 = 0; c2 < 2; ++c2) {
      const float lb = latb[w*32 + c2*16 + lr];
      #pragma unroll
      for (int n = 0; n < 5; ++n) {
        #pragma unroll
        for (int e = 0; e < 4; ++e) {
          float x = lacc[n][c2][e] + lb;
          x = x > 0.f ? x : 0.01f * x;
          agg[c2][e] += p[n][e] * x;
        }
      }
    }
  }
  // agg -> sProj (proj input, bf16 swz). Overwrites sEgoH2 (dead).
  #pragma unroll
  for (int c2 = 0; c2 < 2; ++c2)
    #pragma unroll
    for (int e = 0; e < 4; ++e)
      lds_store_bf16(sProj, lg*4 + e, w*32 + c2*16 + lr, (__bf16)agg[c2][e]);
  __syncthreads();

  // ---- phase 8: proj (16x256)@(256x64); waves 0..3 -> cols w*16..w*16+15
  if (w < 4) {
    const __bf16* WT = ws + OFF_PROJ;
    f32x4 pacc = f32x4{0.f,0.f,0.f,0.f};
    #pragma unroll
    for (int kc = 0; kc < 8; kc += 4) {
      bf16x8 bfr[4];
      #pragma unroll
      for (int j = 0; j < 4; ++j)
        bfr[j] = *reinterpret_cast<const bf16x8*>(WT + (w*16+lr)*256 + (kc+j)*32 + lg*8);
      bf16x8 af[4];
      #pragma unroll
      for (int j = 0; j < 4; ++j)
        af[j] = lds_loadA(sProj, lr, (kc+j)*64 + lg*16, 512);
      #pragma unroll
      for (int j = 0; j < 4; ++j)
        pacc = __builtin_amdgcn_mfma_f32_16x16x32_bf16(af[j], bfr[j], pacc, 0, 0, 0);
    }
    const float pb = projb[w*16 + lr];
    #pragma unroll
    for (int e = 0; e < 4; ++e)
      sOutF[(lg*4 + e)*64 + w*16 + lr] = pacc[e] + pb;
  }
  __syncthreads();

  // ---- phase 9: coalesced NT float4 writes of out[:, 48:112]
  if (tid < 256) {
    int row = tid >> 4, q = tid & 15;
    f32x4 v = *reinterpret_cast<const f32x4*>(sOutF + row*64 + q*4);
    __builtin_nontemporal_store(v,
        reinterpret_cast<f32x4*>(out + (size_t)(b0+row)*112 + 48 + q*4));
  }
}

extern "C" void kernel_launch(void* const* d_in, const int* in_sizes, int n_in,
                              void* d_out, int out_size, void* d_ws, size_t ws_size,
                              hipStream_t stream) {
  const float* obs   = (const float*)d_in[0];
  const float* ew0   = (const float*)d_in[1];
  const float* eb0   = (const float*)d_in[2];
  const float* ew1   = (const float*)d_in[3];
  const float* eb1   = (const float*)d_in[4];
  const float* aw0   = (const float*)d_in[5];
  const float* ab0   = (const float*)d_in[6];
  const float* aw1   = (const float*)d_in[7];
  const float* ab1   = (const float*)d_in[8];
  const float* keyw  = (const float*)d_in[9];
  const float* selw  = (const float*)d_in[10];
  const float* latw  = (const float*)d_in[11];
  const float* latb  = (const float*)d_in[12];
  const float* projw = (const float*)d_in[13];
  const float* projb = (const float*)d_in[14];
  __bf16* ws = (__bf16*)d_ws;
  float* out = (float*)d_out;

  prep_weights<<<dim3((WS_ELEMS + 255)/256), dim3(256), 0, stream>>>(
      ew0, ew1, aw0, aw1, keyw, selw, latw, projw, ws);
  fused_kernel<<<dim3(65536/16), dim3(512), 0, stream>>>(
      obs, eb0, eb1, ab0, ab1, latb, projb, ws, out);
}